// Round 7
// baseline (3923.546 us; speedup 1.0000x reference)
//
#include <hip/hip_runtime.h>

#define HW_ (256 * 256)

typedef float v2f __attribute__((ext_vector_type(2)));

#define CE_ASC(arr, i, l)                  \
  {                                        \
    const float _a = arr[i], _b = arr[l];  \
    arr[i] = fminf(_a, _b);                \
    arr[l] = fmaxf(_a, _b);                \
  }
#define CE_DESC(arr, i, l)                 \
  {                                        \
    const float _a = arr[i], _b = arr[l];  \
    arr[i] = fmaxf(_a, _b);                \
    arr[l] = fminf(_a, _b);                \
  }

// np-einsum-bit-exact score for key kt (4-lane SSE accumulator, NO fma,
// lane_j = ((p_j+p_{j+4})+p_{j+8})+p_{j+12}, horizontal (L0+L1)+(L2+L3)).
// Used in BOTH passes; identical tree + contract(off) -> bit-identical values.
#define SCORE_AT(kt, dst)                                                     \
  {                                                                           \
    const float4 kq0 = *reinterpret_cast<const float4*>(kl + 0 * 256 + (kt) * 4); \
    const float4 kq1 = *reinterpret_cast<const float4*>(kl + 1 * 256 + (kt) * 4); \
    const float4 kq2 = *reinterpret_cast<const float4*>(kl + 2 * 256 + (kt) * 4); \
    const float4 kq3 = *reinterpret_cast<const float4*>(kl + 3 * 256 + (kt) * 4); \
    const v2f P0 = qv[0] * (v2f){kq0.x, kq0.y};                               \
    const v2f P1 = qv[1] * (v2f){kq0.z, kq0.w};                               \
    const v2f P2 = qv[2] * (v2f){kq1.x, kq1.y};                               \
    const v2f P3 = qv[3] * (v2f){kq1.z, kq1.w};                               \
    const v2f P4 = qv[4] * (v2f){kq2.x, kq2.y};                               \
    const v2f P5 = qv[5] * (v2f){kq2.z, kq2.w};                               \
    const v2f P6 = qv[6] * (v2f){kq3.x, kq3.y};                               \
    const v2f P7 = qv[7] * (v2f){kq3.z, kq3.w};                               \
    const v2f L01 = ((P0 + P2) + P4) + P6;                                    \
    const v2f L23 = ((P1 + P3) + P5) + P7;                                    \
    dst = (L01.x + L01.y) + (L23.x + L23.y);                                  \
  }

// One wave (64 threads) handles one (window, head) unit.
// Block = 256 threads = 4 units sharing the same (b, h, wn), wm = 4 consecutive.
// Thread t = query row; scores are RECOMPUTED in pass 2 (no s[64] -> no spill).
__global__ __launch_bounds__(256, 4)
void slice_attn_kernel(const float* __restrict__ Q,
                       const float* __restrict__ K,
                       const float* __restrict__ V,
                       const float* __restrict__ RT,
                       float* __restrict__ O) {
  // [unit][quad][kt][4] layout: staging writes 8-way max; reads wave-uniform.
  __shared__ __align__(16) float k_lds[4][1024];
  __shared__ __align__(16) float v_lds[4][1024];
  __shared__ float bias_lds[225];  // rel-pos column for this head

  const int tid  = threadIdx.x;
  const int wave = tid >> 6;
  const int t    = tid & 63;
  const int bid  = blockIdx.x;

  // decode (b, h, wn, wm) with wm innermost for L2 locality
  const int wm = ((bid & 7) << 2) | wave;
  const int wn = (bid >> 3) & 31;
  const int h  = (bid >> 8) & 7;
  const int b  = bid >> 11;

  if (tid < 225) bias_lds[tid] = RT[tid * 8 + h];

  const int sh = t >> 3, sw = t & 7;
  const int y  = wn * 8 + sh;
  const int x  = wm * 8 + sw;
  const int xs = (x - 4) & 255;  // rolled-right-by-4 source column (wraps at wm==0)

  const int base = (b * 128 + h * 16) * HW_;
  const float* qp = Q + base + y * 256 + x;
  const float* kp = K + base + y * 256 + xs;
  const float* vp = V + base + y * 256 + xs;

  float* kl = k_lds[wave];
  float* vl = v_lds[wave];

  v2f qv[8];
  #pragma unroll
  for (int q4 = 0; q4 < 4; ++q4) {
    float4 kv, vv;
    kv.x = kp[(q4 * 4 + 0) * HW_];
    kv.y = kp[(q4 * 4 + 1) * HW_];
    kv.z = kp[(q4 * 4 + 2) * HW_];
    kv.w = kp[(q4 * 4 + 3) * HW_];
    vv.x = vp[(q4 * 4 + 0) * HW_];
    vv.y = vp[(q4 * 4 + 1) * HW_];
    vv.z = vp[(q4 * 4 + 2) * HW_];
    vv.w = vp[(q4 * 4 + 3) * HW_];
    *reinterpret_cast<float4*>(kl + q4 * 256 + t * 4) = kv;
    *reinterpret_cast<float4*>(vl + q4 * 256 + t * 4) = vv;
    // q * SCALE (0.25 is a power of 2 -> exact)
    qv[2 * q4 + 0].x = qp[(q4 * 4 + 0) * HW_] * 0.25f;
    qv[2 * q4 + 0].y = qp[(q4 * 4 + 1) * HW_] * 0.25f;
    qv[2 * q4 + 1].x = qp[(q4 * 4 + 2) * HW_] * 0.25f;
    qv[2 * q4 + 1].y = qp[(q4 * 4 + 3) * HW_] * 0.25f;
  }
  __syncthreads();

  // ---- PASS 1: streaming top-16 over 4 chunks of 16 keys.
  float A[16];
  {
    #pragma clang fp contract(off)
    #pragma unroll
    for (int c4 = 0; c4 < 4; ++c4) {
      float c[16];
      #pragma unroll
      for (int kk = 0; kk < 16; ++kk) {
        SCORE_AT(c4 * 16 + kk, c[kk])
      }
      // bitonic sort16 ascending (80 CE, all compile-time indices)
      #pragma unroll
      for (int k = 2; k <= 16; k <<= 1) {
        #pragma unroll
        for (int j = k >> 1; j > 0; j >>= 1) {
          #pragma unroll
          for (int i = 0; i < 16; ++i) {
            const int l = i ^ j;
            if (l > i) {
              if ((i & k) == 0) { CE_ASC(c, i, l) } else { CE_DESC(c, i, l) }
            }
          }
        }
      }
      if (c4 == 0) {
        #pragma unroll
        for (int i = 0; i < 16; ++i) A[i] = c[i];
      } else {
        // top-16 of (A asc) U (c asc): half-cleaner vs reversed c -> bitonic,
        // then bitonic-merge ascending. (Correctness HW-verified round 6.)
        float hm[16];
        #pragma unroll
        for (int i = 0; i < 16; ++i) hm[i] = fmaxf(A[i], c[15 - i]);
        #pragma unroll
        for (int j = 8; j > 0; j >>= 1) {
          #pragma unroll
          for (int i = 0; i < 16; ++i) {
            const int l = i ^ j;
            if (l > i) CE_ASC(hm, i, l)
          }
        }
        #pragma unroll
        for (int i = 0; i < 16; ++i) A[i] = hm[i];
      }
    }
  }

  const float thr = A[0];   // 16th largest (exact member of the score set)
  const float m   = A[15];  // pre-bias max (bias |.|<=~0.1 -> safe shift)
  // strictly-greater count: every value > thr is inside the sorted top-16
  int cgt = 0;
  #pragma unroll
  for (int i = 1; i < 16; ++i) cgt += (A[i] > thr) ? 1 : 0;

  // ---- PASS 2: recompute score (bit-identical) + selection (index-ordered
  //      tie quota) + bias + exp + denom (all 64) + packed-fma PV.
  const int vbase = sh * 15 + sw;  // ridx = vbase + (112 - kh*15 - kw), in [0,224]
  const float* bp = &bias_lds[vbase];
  const bool edge = (wm == 0);

  v2f av[8];
  #pragma unroll
  for (int j = 0; j < 8; ++j) av[j] = (v2f){0.0f, 0.0f};
  float d0 = 0.0f, d1 = 0.0f;
  int cnt = cgt;
  {
    #pragma clang fp contract(off)
    #pragma unroll
    for (int i = 0; i < 64; ++i) {
      float sv;
      SCORE_AT(i, sv)
      const bool eq = (sv == thr);
      bool take = (sv > thr) || (eq && (cnt < 16));
      cnt += eq ? 1 : 0;
      if (edge && (i & 7) < 4) take = false;  // post-softmax column mask
      const float bv = bp[112 - (i >> 3) * 15 - (i & 7)];
      const float p  = __expf(sv + bv - m);
      if (i & 1) d1 += p; else d0 += p;       // denominator over ALL 64
      const float w = take ? p : 0.0f;
      const v2f w2 = (v2f){w, w};
      const float4 vq0 = *reinterpret_cast<const float4*>(vl + 0 * 256 + i * 4);
      const float4 vq1 = *reinterpret_cast<const float4*>(vl + 1 * 256 + i * 4);
      const float4 vq2 = *reinterpret_cast<const float4*>(vl + 2 * 256 + i * 4);
      const float4 vq3 = *reinterpret_cast<const float4*>(vl + 3 * 256 + i * 4);
      av[0] += w2 * (v2f){vq0.x, vq0.y};
      av[1] += w2 * (v2f){vq0.z, vq0.w};
      av[2] += w2 * (v2f){vq1.x, vq1.y};
      av[3] += w2 * (v2f){vq1.z, vq1.w};
      av[4] += w2 * (v2f){vq2.x, vq2.y};
      av[5] += w2 * (v2f){vq2.z, vq2.w};
      av[6] += w2 * (v2f){vq3.x, vq3.y};
      av[7] += w2 * (v2f){vq3.z, vq3.w};
    }
  }
  const float inv = 1.0f / (d0 + d1);
  const v2f inv2 = (v2f){inv, inv};
  #pragma unroll
  for (int j = 0; j < 8; ++j) av[j] *= inv2;

  // ---- store (channel cc = 2j / 2j+1)
  float* op = O + base + y * 256 + x;
  #pragma unroll
  for (int j = 0; j < 8; ++j) {
    op[(2 * j + 0) * HW_] = av[j].x;
    op[(2 * j + 1) * HW_] = av[j].y;
  }
}

extern "C" void kernel_launch(void* const* d_in, const int* in_sizes, int n_in,
                              void* d_out, int out_size, void* d_ws, size_t ws_size,
                              hipStream_t stream) {
  const float* Q  = (const float*)d_in[0];
  const float* K  = (const float*)d_in[1];
  const float* V  = (const float*)d_in[2];
  const float* RT = (const float*)d_in[3];
  float* O = (float*)d_out;
  dim3 grid(4096), block(256);
  hipLaunchKernelGGL(slice_attn_kernel, grid, block, 0, stream, Q, K, V, RT, O);
}

// Round 8
// 1678.015 us; speedup vs baseline: 2.3382x; 2.3382x over previous
//
#include <hip/hip_runtime.h>

#define HW_ (256 * 256)

typedef float v2f __attribute__((ext_vector_type(2)));

#define CE_ASC(arr, i, l)                  \
  {                                        \
    const float _a = arr[i], _b = arr[l];  \
    arr[i] = fminf(_a, _b);                \
    arr[l] = fmaxf(_a, _b);                \
  }
#define CE_DESC(arr, i, l)                 \
  {                                        \
    const float _a = arr[i], _b = arr[l];  \
    arr[i] = fmaxf(_a, _b);                \
    arr[l] = fminf(_a, _b);                \
  }

// Decomposition: thread = (query row, key-half). Wave = 32 rows x 2 key-halves.
// 2 waves per (window,head) unit; block = 256 threads = 2 units.
// Partner lane (lane^32) holds the other 32 keys of the same row.
__global__ __launch_bounds__(256, 4)
void slice_attn_kernel(const float* __restrict__ Q,
                       const float* __restrict__ K,
                       const float* __restrict__ V,
                       const float* __restrict__ RT,
                       float* __restrict__ O) {
  // [unit][quad][kt][4]: b128 staging writes at the inherent 8-way wave64 floor;
  // score/PV reads are 2-address broadcasts (conflict-free).
  __shared__ __align__(16) float k_lds[2][1024];
  __shared__ __align__(16) float v_lds[2][1024];
  __shared__ float bias_lds[225];  // rel-pos column for this head

  const int tid  = threadIdx.x;
  const int wave = tid >> 6;
  const int lane = tid & 63;
  const int bid  = blockIdx.x;

  const int w2       = wave >> 1;   // unit within block
  const int waveHalf = wave & 1;    // row group (also staging role: K vs V)
  const int keyHalf  = lane >> 5;   // key group within row
  const int row      = waveHalf * 32 + (lane & 31);

  // unit decode, wm innermost for L2 locality
  const int unit = bid * 2 + w2;
  const int wm = unit & 31;
  const int wn = (unit >> 5) & 31;
  const int h  = (unit >> 10) & 7;
  const int b  = unit >> 13;

  if (tid < 225) bias_lds[tid] = RT[tid * 8 + h];

  const int base = (b * 128 + h * 16) * HW_;

  // ---- stage K (wave 0 of unit) / V (wave 1 of unit): lane -> key token
  {
    const int kt_s = lane;
    const int kh = kt_s >> 3, kw = kt_s & 7;
    const int yk = wn * 8 + kh;
    const int xk = (wm * 8 + kw - 4) & 255;  // roll right by 4 (wraps at wm==0)
    const float* sp = (waveHalf == 0 ? K : V) + base + yk * 256 + xk;
    float* dl = (waveHalf == 0 ? k_lds[w2] : v_lds[w2]);
    #pragma unroll
    for (int q4 = 0; q4 < 4; ++q4) {
      float4 vvv;
      vvv.x = sp[(q4 * 4 + 0) * HW_];
      vvv.y = sp[(q4 * 4 + 1) * HW_];
      vvv.z = sp[(q4 * 4 + 2) * HW_];
      vvv.w = sp[(q4 * 4 + 3) * HW_];
      *reinterpret_cast<float4*>(dl + q4 * 256 + kt_s * 4) = vvv;
    }
  }

  // ---- q for this row (both key-halves load the same addresses: cache-served)
  const int sh = row >> 3, sw = row & 7;
  const int y = wn * 8 + sh, x = wm * 8 + sw;
  const float* qp = Q + base + y * 256 + x;
  v2f qv[8];
  #pragma unroll
  for (int q4 = 0; q4 < 4; ++q4) {
    qv[2 * q4 + 0].x = qp[(q4 * 4 + 0) * HW_] * 0.25f;  // *SCALE, pow2 exact
    qv[2 * q4 + 0].y = qp[(q4 * 4 + 1) * HW_] * 0.25f;
    qv[2 * q4 + 1].x = qp[(q4 * 4 + 2) * HW_] * 0.25f;
    qv[2 * q4 + 1].y = qp[(q4 * 4 + 3) * HW_] * 0.25f;
  }
  __syncthreads();

  const float* kl = k_lds[w2];
  const float* vl = v_lds[w2];

  // ---- PASS 1: 32 scores (np-einsum-bit-exact tree: 4-lane SSE accumulator,
  //      NO fma, lane_j = ((p_j+p_{j+4})+p_{j+8})+p_{j+12}, (L0+L1)+(L2+L3)),
  //      streaming top-16 over two 16-chunks (sort16 + merge, r6-verified).
  float s[32];
  float A[16];
  {
    #pragma clang fp contract(off)
    #pragma unroll
    for (int ch = 0; ch < 2; ++ch) {
      float c[16];
      #pragma unroll
      for (int kk = 0; kk < 16; ++kk) {
        const int kt = keyHalf * 32 + ch * 16 + kk;
        const float4 kq0 = *reinterpret_cast<const float4*>(kl + 0 * 256 + kt * 4);
        const float4 kq1 = *reinterpret_cast<const float4*>(kl + 1 * 256 + kt * 4);
        const float4 kq2 = *reinterpret_cast<const float4*>(kl + 2 * 256 + kt * 4);
        const float4 kq3 = *reinterpret_cast<const float4*>(kl + 3 * 256 + kt * 4);
        const v2f P0 = qv[0] * (v2f){kq0.x, kq0.y};
        const v2f P1 = qv[1] * (v2f){kq0.z, kq0.w};
        const v2f P2 = qv[2] * (v2f){kq1.x, kq1.y};
        const v2f P3 = qv[3] * (v2f){kq1.z, kq1.w};
        const v2f P4 = qv[4] * (v2f){kq2.x, kq2.y};
        const v2f P5 = qv[5] * (v2f){kq2.z, kq2.w};
        const v2f P6 = qv[6] * (v2f){kq3.x, kq3.y};
        const v2f P7 = qv[7] * (v2f){kq3.z, kq3.w};
        const v2f L01 = ((P0 + P2) + P4) + P6;
        const v2f L23 = ((P1 + P3) + P5) + P7;
        const float val = (L01.x + L01.y) + (L23.x + L23.y);
        c[kk] = val;
        s[ch * 16 + kk] = val;
      }
      // bitonic sort16 ascending
      #pragma unroll
      for (int k = 2; k <= 16; k <<= 1) {
        #pragma unroll
        for (int j = k >> 1; j > 0; j >>= 1) {
          #pragma unroll
          for (int i = 0; i < 16; ++i) {
            const int l = i ^ j;
            if (l > i) {
              if ((i & k) == 0) { CE_ASC(c, i, l) } else { CE_DESC(c, i, l) }
            }
          }
        }
      }
      if (ch == 0) {
        #pragma unroll
        for (int i = 0; i < 16; ++i) A[i] = c[i];
      } else {
        float hm[16];
        #pragma unroll
        for (int i = 0; i < 16; ++i) hm[i] = fmaxf(A[i], c[15 - i]);
        #pragma unroll
        for (int j = 8; j > 0; j >>= 1) {
          #pragma unroll
          for (int i = 0; i < 16; ++i) {
            const int l = i ^ j;
            if (l > i) CE_ASC(hm, i, l)
          }
        }
        #pragma unroll
        for (int i = 0; i < 16; ++i) A[i] = hm[i];
      }
    }
  }

  // ---- cross-lane merge with partner (other 32 keys of the same row):
  //      both lanes compute the identical global ascending top-16.
  {
    float Ao[16];
    #pragma unroll
    for (int i = 0; i < 16; ++i) Ao[i] = __shfl_xor(A[i], 32);
    float hm[16];
    #pragma unroll
    for (int i = 0; i < 16; ++i) hm[i] = fmaxf(A[i], Ao[15 - i]);
    #pragma unroll
    for (int j = 8; j > 0; j >>= 1) {
      #pragma unroll
      for (int i = 0; i < 16; ++i) {
        const int l = i ^ j;
        if (l > i) CE_ASC(hm, i, l)
      }
    }
    #pragma unroll
    for (int i = 0; i < 16; ++i) A[i] = hm[i];
  }

  const float thr = A[0];   // 16th largest (exact member of the score set)
  const float m   = A[15];  // pre-bias max (bias |.|<=~0.1 -> safe shift)
  int cgt = 0;              // strictly-greater count (all >thr are in top-16)
  #pragma unroll
  for (int i = 1; i < 16; ++i) cgt += (A[i] > thr) ? 1 : 0;

  // tie bookkeeping for global index-ordered quota: half 1's scan starts after
  // all of half 0's ties (seen, whether taken or not).
  int eq_own = 0;
  #pragma unroll
  for (int j = 0; j < 32; ++j) eq_own += (s[j] == thr) ? 1 : 0;
  const int eq_other = __shfl_xor(eq_own, 32);
  int cnt = cgt + (keyHalf ? eq_other : 0);

  // ---- PASS 2: selection + bias + exp + denom + packed-fma PV over own 32 keys
  const int vbase = sh * 15 + sw;  // ridx = vbase + (112 - kh*15 - kw)
  const float* bp = &bias_lds[vbase];
  const bool edge = (wm == 0);

  v2f av[8];
  #pragma unroll
  for (int j = 0; j < 8; ++j) av[j] = (v2f){0.0f, 0.0f};
  float d0 = 0.0f, d1 = 0.0f;
  #pragma unroll
  for (int j = 0; j < 32; ++j) {
    const int ig = keyHalf * 32 + j;   // global key index
    const float sv = s[j];
    const bool eq = (sv == thr);
    bool take = (sv > thr) || (eq && (cnt < 16));
    cnt += eq ? 1 : 0;
    if (edge && (j & 7) < 4) take = false;  // post-softmax column mask
    const float bv = bp[112 - (ig >> 3) * 15 - (ig & 7)];
    const float p  = __expf(sv + bv - m);
    if (j & 1) d1 += p; else d0 += p;        // partial denominator
    const float w = take ? p : 0.0f;
    const v2f w2v = (v2f){w, w};
    const float4 vq0 = *reinterpret_cast<const float4*>(vl + 0 * 256 + ig * 4);
    const float4 vq1 = *reinterpret_cast<const float4*>(vl + 1 * 256 + ig * 4);
    const float4 vq2 = *reinterpret_cast<const float4*>(vl + 2 * 256 + ig * 4);
    const float4 vq3 = *reinterpret_cast<const float4*>(vl + 3 * 256 + ig * 4);
    av[0] += w2v * (v2f){vq0.x, vq0.y};
    av[1] += w2v * (v2f){vq0.z, vq0.w};
    av[2] += w2v * (v2f){vq1.x, vq1.y};
    av[3] += w2v * (v2f){vq1.z, vq1.w};
    av[4] += w2v * (v2f){vq2.x, vq2.y};
    av[5] += w2v * (v2f){vq2.z, vq2.w};
    av[6] += w2v * (v2f){vq3.x, vq3.y};
    av[7] += w2v * (v2f){vq3.z, vq3.w};
  }

  // total denominator across the pair
  float d = d0 + d1;
  d += __shfl_xor(d, 32);
  const float inv = 1.0f / d;

  // ---- cross-lane PV reduce: send the half I do NOT write; receive mine.
  //      Lane writes channels [keyHalf*8, keyHalf*8+8).
  float outv[8];
  #pragma unroll
  for (int j = 0; j < 4; ++j) {
    const v2f snd  = av[(1 - keyHalf) * 4 + j];
    const float rx = __shfl_xor(snd.x, 32);
    const float ry = __shfl_xor(snd.y, 32);
    const v2f mine = av[keyHalf * 4 + j];
    outv[2 * j + 0] = (mine.x + rx) * inv;
    outv[2 * j + 1] = (mine.y + ry) * inv;
  }

  // ---- store 8 channels
  float* op = O + base + y * 256 + x + (keyHalf * 8) * HW_;
  #pragma unroll
  for (int j = 0; j < 8; ++j) op[j * HW_] = outv[j];
}

extern "C" void kernel_launch(void* const* d_in, const int* in_sizes, int n_in,
                              void* d_out, int out_size, void* d_ws, size_t ws_size,
                              hipStream_t stream) {
  const float* Q  = (const float*)d_in[0];
  const float* K  = (const float*)d_in[1];
  const float* V  = (const float*)d_in[2];
  const float* RT = (const float*)d_in[3];
  float* O = (float*)d_out;
  dim3 grid(8192), block(256);
  hipLaunchKernelGGL(slice_attn_kernel, grid, block, 0, stream, Q, K, V, RT, O);
}